// Round 5
// baseline (14.669 us; speedup 1.0000x reference)
//
#include <hip/hip_runtime.h>
#include <math.h>

// Problem constants (from setup_inputs): bs=2, Q=256, C=16, P=20, T=256
#define BS    2
#define NQ    256
#define NCLS  16
#define NP    20
#define NT    256
#define NN    (BS * NQ)    // 512 predictions
#define FEPS  1e-6f
#define QPL   5            // target points per lane (NP / 4)
#define TPB   64           // targets per block
#define PHALF 10           // p-chunk per butterfly batch
#define THREADS 256

// Grid: NN * (NT/TPB) = 2048 blocks x 256 threads = 8192 waves (8 / SIMD).
// NO LDS, NO __syncthreads: pred polyline + logits are block-uniform and are
// loaded via compile-time-indexed uniform addresses -> compiler scalarizes to
// s_load (SGPRs). Inner p-loop is pure VALU with SGPR pred operands; per-lane
// target state is only 15 VGPRs (tx/ty/m2), so natural VGPR count stays low
// (~8 waves/SIMD) without forcing launch bounds. Quad butterflies are bulk,
// after each 10-p half, and lower to DPP quad_perm (VALU-speed).
__global__ __launch_bounds__(THREADS) void matcher_cost_kernel(
    const float* __restrict__ logits,   // [NN, NCLS]
    const float* __restrict__ ppoly,    // [NN, NP, 2]
    const int*   __restrict__ tlabels,  // [NT]
    const float* __restrict__ tpoly,    // [NT, NP, 2]
    float*       __restrict__ out)      // [NN, NT]
{
    const int bid   = blockIdx.x;            // 0..2047
    const int n     = bid >> 2;              // prediction index (uniform)
    const int tbase = (bid & 3) * TPB;
    const int tid   = threadIdx.x;           // 0..255
    const int t     = tbase + (tid >> 2);    // target index
    const int z     = tid & 3;               // q-quarter

    // --- block-uniform pred polyline + logits -> SGPRs (s_load) ---
    float px[NP], py[NP];
    const float* pp = ppoly + n * NP * 2;
    #pragma unroll
    for (int p = 0; p < NP; ++p) { px[p] = pp[2 * p]; py[p] = pp[2 * p + 1]; }

    float lg[NCLS];
    const float* lp = logits + n * NCLS;
    #pragma unroll
    for (int c = 0; c < NCLS; ++c) lg[c] = lp[c];

    // --- per-lane target points (5 per lane): float4,float4,float2 ---
    float tx[QPL], ty[QPL], m2[QPL];
    {
        const float* tp = &tpoly[(t * NP + z * QPL) * 2];
        float4 a = *reinterpret_cast<const float4*>(tp);
        float4 b = *reinterpret_cast<const float4*>(tp + 4);
        float2 c = *reinterpret_cast<const float2*>(tp + 8);
        tx[0] = a.x; ty[0] = a.y; tx[1] = a.z; ty[1] = a.w;
        tx[2] = b.x; ty[2] = b.y; tx[3] = b.z; ty[3] = b.w;
        tx[4] = c.x; ty[4] = c.y;
        #pragma unroll
        for (int k = 0; k < QPL; ++k) m2[k] = 1e30f;
    }

    // --- polyline cost: pure-VALU inner loop, bulk DPP butterflies per half ---
    float sum1 = 0.f;
    #pragma unroll
    for (int h = 0; h < 2; ++h) {
        float m1a[PHALF];
        #pragma unroll
        for (int pp2 = 0; pp2 < PHALF; ++pp2) {
            const int p = h * PHALF + pp2;
            const float vx = px[p];   // SGPR operand
            const float vy = py[p];
            const float d0 = fabsf(vx - tx[0]) + fabsf(vy - ty[0]);
            const float d1 = fabsf(vx - tx[1]) + fabsf(vy - ty[1]);
            const float d2 = fabsf(vx - tx[2]) + fabsf(vy - ty[2]);
            const float d3 = fabsf(vx - tx[3]) + fabsf(vy - ty[3]);
            const float d4 = fabsf(vx - tx[4]) + fabsf(vy - ty[4]);
            m2[0] = fminf(m2[0], d0);
            m2[1] = fminf(m2[1], d1);
            m2[2] = fminf(m2[2], d2);
            m2[3] = fminf(m2[3], d3);
            m2[4] = fminf(m2[4], d4);
            m1a[pp2] = fminf(fminf(fminf(d0, d1), d2), fminf(d3, d4));
        }
        // bulk quad-butterfly: 10 independent chains (DPP quad_perm)
        float s = 0.f;
        #pragma unroll
        for (int pp2 = 0; pp2 < PHALF; ++pp2) {
            float v = m1a[pp2];
            v = fminf(v, __shfl_xor(v, 1, 4));
            v = fminf(v, __shfl_xor(v, 2, 4));
            s += v;
        }
        sum1 += s;
    }
    float sum2 = ((m2[0] + m2[1]) + (m2[2] + m2[3])) + m2[4];
    sum2 += __shfl_xor(sum2, 1, 4);
    sum2 += __shfl_xor(sum2, 2, 4);
    const float cost_poly = (sum1 + sum2) * (0.5f / (float)NP);

    // --- target endpoints: q=0 lives in lane z=0, q=19 in lane z=3 ---
    const float g1x = __shfl_xor(tx[QPL - 1], 3, 4);  // lane0 <- lane3
    const float g1y = __shfl_xor(ty[QPL - 1], 3, 4);

    if (z == 0) {
        // --- classification: softmax from SGPR logits (uniform VALU) ---
        float mx = lg[0];
        #pragma unroll
        for (int c = 1; c < NCLS; ++c) mx = fmaxf(mx, lg[c]);
        float den = 0.f, pl = 0.f;
        const int lbl = tlabels[t];
        #pragma unroll
        for (int c = 0; c < NCLS; ++c) {
            const float e = __expf(lg[c] - mx);
            den += e;
            if (c == lbl) pl = e;   // lbl is per-lane; select via cndmask
        }
        const float cost_class = -pl / den;

        // --- direction cost ---
        float pdx = px[NP - 1] - px[0];
        float pdy = py[NP - 1] - py[0];
        const float pn = sqrtf(pdx * pdx + pdy * pdy) + FEPS;
        const float gdx = g1x - tx[0];
        const float gdy = g1y - ty[0];
        const float gn = sqrtf(gdx * gdx + gdy * gdy) + FEPS;
        const float cost_dir = 1.f - (pdx * gdx + pdy * gdy) / (pn * gn);

        out[n * NT + t] = cost_class + cost_poly + cost_dir;
    }
}

extern "C" void kernel_launch(void* const* d_in, const int* in_sizes, int n_in,
                              void* d_out, int out_size, void* d_ws, size_t ws_size,
                              hipStream_t stream) {
    const float* logits  = (const float*)d_in[0];  // [2,256,16]
    const float* ppoly   = (const float*)d_in[1];  // [2,256,20,2]
    const int*   tlabels = (const int*)d_in[2];    // [256]
    const float* tpoly   = (const float*)d_in[3];  // [256,20,2]
    float*       out     = (float*)d_out;          // [2,256,256]

    matcher_cost_kernel<<<dim3(NN * (NT / TPB)), dim3(THREADS), 0, stream>>>(
        logits, ppoly, tlabels, tpoly, out);
}

// Round 6
// 13.276 us; speedup vs baseline: 1.1049x; 1.1049x over previous
//
#include <hip/hip_runtime.h>
#include <math.h>

// Problem constants (from setup_inputs): bs=2, Q=256, C=16, P=20, T=256
#define BS    2
#define NQ    256
#define NCLS  16
#define NP    20
#define NT    256
#define NN    (BS * NQ)    // 512 predictions
#define FEPS  1e-6f
#define QPL   5            // target points per lane (NP / 4)
#define TPB   128          // targets per block
#define PHALF 10           // p-chunk per butterfly batch
#define THREADS (TPB * 4)  // 512 threads = 8 waves

// Grid: NN * (NT/TPB) = 1024 blocks x 8 waves = 8192 waves; 4 blocks/CU x 8
// waves = 32 waves/CU (max occupancy). Quad of lanes handles one target t;
// lane z owns target points q in [5z,5z+5) -> per-thread state is only
// tx/ty/m2 = 15 floats (lowest op count + shortest chains of all tested
// decompositions). Inner p-loop is pure VALU (uniform LDS broadcast + min3
// trees); quad butterflies done in bulk after each 10-p half. Softmax pieces
// computed once per block into LDS (single __syncthreads).
__global__ __launch_bounds__(THREADS) void matcher_cost_kernel(
    const float* __restrict__ logits,   // [NN, NCLS]
    const float* __restrict__ ppoly,    // [NN, NP, 2]
    const int*   __restrict__ tlabels,  // [NT]
    const float* __restrict__ tpoly,    // [NT, NP, 2]
    float*       __restrict__ out)      // [NN, NT]
{
    const int bid   = blockIdx.x;            // 0..1023
    const int n     = bid >> 1;              // prediction index
    const int tbase = (bid & 1) * TPB;
    const int tid   = threadIdx.x;           // 0..511
    const int t     = tbase + (tid >> 2);    // target index
    const int z     = tid & 3;               // q-quarter

    __shared__ float2 s_pxy[NP];             // pred polyline
    __shared__ float  s_prob[NCLS];          // exp(logit - max)
    __shared__ float  s_invden;              // 1/sum(exp)
    __shared__ float  s_dir[2];              // normalized pred direction

    // --- stage pred polyline; wave 0 computes softmax pieces + direction ---
    if (tid < NP * 2) ((float*)s_pxy)[tid] = ppoly[n * NP * 2 + tid];
    if (tid < NCLS) {
        const float* lp = logits + n * NCLS;
        float mx = lp[0];
        #pragma unroll
        for (int c = 1; c < NCLS; ++c) mx = fmaxf(fmaxf(mx, lp[c]), mx); // max3 fuse ok
        s_prob[tid] = __expf(lp[tid] - mx);
    }
    __syncthreads();
    if (tid == 0) {
        float den = 0.f;
        #pragma unroll
        for (int c = 0; c < NCLS; ++c) den += s_prob[c];
        s_invden = 1.f / den;
        float2 a = s_pxy[0], b = s_pxy[NP - 1];
        float dx = b.x - a.x, dy = b.y - a.y;
        float nrm = sqrtf(dx * dx + dy * dy) + FEPS;
        s_dir[0] = dx / nrm; s_dir[1] = dy / nrm;
    }

    // --- per-lane target points (5 per lane) ---
    float tx[QPL], ty[QPL], m2[QPL];
    {
        const float* tp = &tpoly[(t * NP + z * QPL) * 2];
        float4 a = *reinterpret_cast<const float4*>(tp);
        float4 b = *reinterpret_cast<const float4*>(tp + 4);
        float2 c = *reinterpret_cast<const float2*>(tp + 8);
        tx[0] = a.x; ty[0] = a.y; tx[1] = a.z; ty[1] = a.w;
        tx[2] = b.x; ty[2] = b.y; tx[3] = b.z; ty[3] = b.w;
        tx[4] = c.x; ty[4] = c.y;
        #pragma unroll
        for (int k = 0; k < QPL; ++k) m2[k] = 1e30f;
    }

    // --- polyline cost: pure-VALU inner loop, bulk butterflies per half ---
    float sum1 = 0.f;
    #pragma unroll
    for (int h = 0; h < 2; ++h) {
        float m1a[PHALF];
        #pragma unroll
        for (int pp = 0; pp < PHALF; ++pp) {
            const float2 pxy = s_pxy[h * PHALF + pp];   // uniform broadcast
            const float d0 = fabsf(pxy.x - tx[0]) + fabsf(pxy.y - ty[0]);
            const float d1 = fabsf(pxy.x - tx[1]) + fabsf(pxy.y - ty[1]);
            const float d2 = fabsf(pxy.x - tx[2]) + fabsf(pxy.y - ty[2]);
            const float d3 = fabsf(pxy.x - tx[3]) + fabsf(pxy.y - ty[3]);
            const float d4 = fabsf(pxy.x - tx[4]) + fabsf(pxy.y - ty[4]);
            m2[0] = fminf(m2[0], d0);
            m2[1] = fminf(m2[1], d1);
            m2[2] = fminf(m2[2], d2);
            m2[3] = fminf(m2[3], d3);
            m2[4] = fminf(m2[4], d4);
            // two v_min3_f32: min(min(d0,d1),d2), then min(min(.,d3),d4)
            const float a01 = fminf(fminf(d0, d1), d2);
            m1a[pp] = fminf(fminf(a01, d3), d4);
        }
        // bulk quad-butterfly: 10 independent chains (DPP quad_perm speed)
        float s = 0.f;
        #pragma unroll
        for (int pp = 0; pp < PHALF; ++pp) {
            float v = m1a[pp];
            v = fminf(v, __shfl_xor(v, 1, 4));
            v = fminf(v, __shfl_xor(v, 2, 4));
            s += v;
        }
        sum1 += s;
    }
    float sum2 = ((m2[0] + m2[1]) + (m2[2] + m2[3])) + m2[4];
    sum2 += __shfl_xor(sum2, 1, 4);
    sum2 += __shfl_xor(sum2, 2, 4);
    const float cost_poly = (sum1 + sum2) * (0.5f / (float)NP);

    // --- target endpoints: q=0 in lane z=0, q=19 in lane z=3 ---
    const float g1x = __shfl_xor(tx[QPL - 1], 3, 4);
    const float g1y = __shfl_xor(ty[QPL - 1], 3, 4);

    if (z == 0) {
        const int lbl = tlabels[t];
        const float cost_class = -s_prob[lbl] * s_invden;

        const float gdx = g1x - tx[0];
        const float gdy = g1y - ty[0];
        const float gn = sqrtf(gdx * gdx + gdy * gdy) + FEPS;
        const float cost_dir = 1.f - (s_dir[0] * gdx + s_dir[1] * gdy) / gn;

        out[n * NT + t] = cost_class + cost_poly + cost_dir;
    }
}

extern "C" void kernel_launch(void* const* d_in, const int* in_sizes, int n_in,
                              void* d_out, int out_size, void* d_ws, size_t ws_size,
                              hipStream_t stream) {
    const float* logits  = (const float*)d_in[0];  // [2,256,16]
    const float* ppoly   = (const float*)d_in[1];  // [2,256,20,2]
    const int*   tlabels = (const int*)d_in[2];    // [256]
    const float* tpoly   = (const float*)d_in[3];  // [256,20,2]
    float*       out     = (float*)d_out;          // [2,256,256]

    matcher_cost_kernel<<<dim3(NN * (NT / TPB)), dim3(THREADS), 0, stream>>>(
        logits, ppoly, tlabels, tpoly, out);
}